// Round 1
// baseline (2674.464 us; speedup 1.0000x reference)
//
#include <hip/hip_runtime.h>
#include <math.h>

// GAT layer: B=16, N=2048, D_IN=D_OUT=256, fp32.
//   h = nodes @ W                        (kernel 1, h -> d_ws, 64 MB)
//   scores = leaky_relu(h @ h^T) * adj   (kernel 2, fused flash-style)
//   out = softmax(scores) @ nodes + bias
constexpr int Bc  = 16;
constexpr int Nn  = 2048;
constexpr int Dd  = 256;
constexpr int QT  = 8;    // query rows per block
constexpr int CH  = 512;  // m-chunk for online softmax
constexpr int NTH = 256;

// ---------------- kernel 1: h[b,n,o] = sum_i nodes[b,n,i] * W[i,o] ----------------
// 8 rows per block; rows staged in LDS (broadcast reads); W reads coalesced across
// lanes and L2-resident (256 KB).
__global__ void __launch_bounds__(256, 4)
h_gemm_kernel(const float* __restrict__ nodes, const float* __restrict__ W,
              float* __restrict__ h)
{
    constexpr int RWS = 8;
    __shared__ float rows[RWS][Dd];
    const int t = threadIdx.x;
    const long long r0 = (long long)blockIdx.x * RWS;
    #pragma unroll
    for (int k = 0; k < RWS; ++k)
        rows[k][t] = nodes[(r0 + k) * Dd + t];
    __syncthreads();
    float acc[RWS] = {};
    for (int i = 0; i < Dd; ++i) {
        const float w = W[i * Dd + t];
        #pragma unroll
        for (int k = 0; k < RWS; ++k) acc[k] = fmaf(rows[k][i], w, acc[k]);
    }
    #pragma unroll
    for (int k = 0; k < RWS; ++k)
        h[(r0 + k) * Dd + t] = acc[k];
}

// ---------------- kernel 2: fused scores + softmax + aggregation ----------------
// One block = 8 query rows of one batch. Online softmax over m in chunks of 512.
// LDS: hq 8KB + sb 16KB + part 32KB = 56KB (2 blocks/CU on the 160KB pool).
__global__ void __launch_bounds__(256, 2)
gat_attn_kernel(const float* __restrict__ h, const float* __restrict__ nodes,
                const float* __restrict__ adj, const float* __restrict__ bias,
                float* __restrict__ out)
{
    __shared__ float hq[QT][Dd];        // query-tile of h
    __shared__ float sb[QT][CH];        // score/prob chunk
    __shared__ float part[4][QT * Dd];  // cross-wave output partials
    __shared__ float alphaS[QT];
    __shared__ float Ls[QT];

    const int t    = threadIdx.x;
    const int wave = t >> 6;
    const int lane = t & 63;
    const int b    = blockIdx.x / (Nn / QT);
    const int q0   = (blockIdx.x % (Nn / QT)) * QT;

    const float* hb = h     + (long long)b * Nn * Dd;
    const float* nb = nodes + (long long)b * Nn * Dd;
    const float* ab = adj   + (long long)b * Nn * Nn + (long long)q0 * Nn;

    #pragma unroll
    for (int q = 0; q < QT; ++q)
        hq[q][t] = hb[(long long)(q0 + q) * Dd + t];

    // online-softmax state, wave w owns q = 2w, 2w+1 (uniform across lanes)
    float Mst[2] = {-1e30f, -1e30f};
    float Lst[2] = {0.f, 0.f};

    const int dg = lane * 4;   // output columns d = dg..dg+3 for this thread
    float4 oacc[QT];
    #pragma unroll
    for (int q = 0; q < QT; ++q) oacc[q] = make_float4(0.f, 0.f, 0.f, 0.f);

    for (int mb = 0; mb < Nn; mb += CH) {
        __syncthreads();  // sb/alphaS reusable; also orders hq init on first iter

        // ---- scores: thread covers m = mb+t and mb+t+256 ----
        {
            const float* hm0 = hb + (long long)(mb + t) * Dd;
            const float* hm1 = hm0 + 256LL * Dd;
            float acc0[QT] = {}, acc1[QT] = {};
            for (int i = 0; i < Dd; i += 4) {
                const float4 v0 = *(const float4*)(hm0 + i);
                const float4 v1 = *(const float4*)(hm1 + i);
                #pragma unroll
                for (int q = 0; q < QT; ++q) {
                    const float4 hv = *(const float4*)&hq[q][i];  // LDS broadcast
                    acc0[q] = fmaf(hv.x, v0.x, fmaf(hv.y, v0.y,
                              fmaf(hv.z, v0.z, fmaf(hv.w, v0.w, acc0[q]))));
                    acc1[q] = fmaf(hv.x, v1.x, fmaf(hv.y, v1.y,
                              fmaf(hv.z, v1.z, fmaf(hv.w, v1.w, acc1[q]))));
                }
            }
            #pragma unroll
            for (int q = 0; q < QT; ++q) {
                float s0 = acc0[q];
                s0 = (s0 >= 0.f) ? s0 : 0.2f * s0;
                s0 *= ab[(long long)q * Nn + mb + t];
                sb[q][t] = s0;
                float s1 = acc1[q];
                s1 = (s1 >= 0.f) ? s1 : 0.2f * s1;
                s1 *= ab[(long long)q * Nn + mb + 256 + t];
                sb[q][t + 256] = s1;
            }
        }
        __syncthreads();

        // ---- online softmax update (wave w handles q = 2w, 2w+1) ----
        #pragma unroll
        for (int qi = 0; qi < 2; ++qi) {
            const int q = wave * 2 + qi;
            float cmax = -1e30f;
            for (int j = lane; j < CH; j += 64) cmax = fmaxf(cmax, sb[q][j]);
            for (int off = 32; off; off >>= 1) cmax = fmaxf(cmax, __shfl_xor(cmax, off));
            const float newM  = fmaxf(Mst[qi], cmax);
            const float alpha = __expf(Mst[qi] - newM);
            float csum = 0.f;
            for (int j = lane; j < CH; j += 64) {
                const float e = __expf(sb[q][j] - newM);
                sb[q][j] = e;
                csum += e;
            }
            for (int off = 32; off; off >>= 1) csum += __shfl_xor(csum, off);
            Lst[qi] = Lst[qi] * alpha + csum;
            Mst[qi] = newM;
            if (lane == 0) alphaS[q] = alpha;
        }
        __syncthreads();

        // ---- aggregation: rescale then accumulate this chunk ----
        #pragma unroll
        for (int q = 0; q < QT; ++q) {
            const float a = alphaS[q];
            oacc[q].x *= a; oacc[q].y *= a; oacc[q].z *= a; oacc[q].w *= a;
        }
        const int mlo = wave * (CH / 4);   // wave's 128 m's within chunk
        for (int k = 0; k < CH / 4; k += 4) {
            const int ml = mlo + k;
            const float* nr = nb + (long long)(mb + ml) * Dd + dg;
            const float4 n0 = *(const float4*)(nr);
            const float4 n1 = *(const float4*)(nr + Dd);
            const float4 n2 = *(const float4*)(nr + 2 * Dd);
            const float4 n3 = *(const float4*)(nr + 3 * Dd);
            #pragma unroll
            for (int q = 0; q < QT; ++q) {
                const float4 p = *(const float4*)&sb[q][ml];   // LDS broadcast
                oacc[q].x = fmaf(p.x, n0.x, fmaf(p.y, n1.x, fmaf(p.z, n2.x, fmaf(p.w, n3.x, oacc[q].x))));
                oacc[q].y = fmaf(p.x, n0.y, fmaf(p.y, n1.y, fmaf(p.z, n2.y, fmaf(p.w, n3.y, oacc[q].y))));
                oacc[q].z = fmaf(p.x, n0.z, fmaf(p.y, n1.z, fmaf(p.z, n2.z, fmaf(p.w, n3.z, oacc[q].z))));
                oacc[q].w = fmaf(p.x, n0.w, fmaf(p.y, n1.w, fmaf(p.z, n2.w, fmaf(p.w, n3.w, oacc[q].w))));
            }
        }
    }

    if (lane == 0) { Ls[wave * 2] = Lst[0]; Ls[wave * 2 + 1] = Lst[1]; }
    __syncthreads();   // all agg reads of sb done; Ls visible

    #pragma unroll
    for (int q = 0; q < QT; ++q)
        *(float4*)&part[wave][q * Dd + dg] = oacc[q];
    __syncthreads();

    // final combine: 2048 outputs, 8 per thread; idx = q*256 + d
    for (int idx = t; idx < QT * Dd; idx += NTH) {
        const int q = idx >> 8;
        const int d = idx & 255;
        float v = part[0][idx] + part[1][idx] + part[2][idx] + part[3][idx];
        v = v / Ls[q] + bias[d];
        out[((long long)b * Nn + q0 + q) * Dd + d] = v;
    }
}

extern "C" void kernel_launch(void* const* d_in, const int* in_sizes, int n_in,
                              void* d_out, int out_size, void* d_ws, size_t ws_size,
                              hipStream_t stream) {
    const float* nodes = (const float*)d_in[0];  // [16,2048,256]
    const float* adj   = (const float*)d_in[1];  // [16,2048,2048]
    const float* W     = (const float*)d_in[2];  // [256,256]
    const float* bias  = (const float*)d_in[3];  // [256]
    float* out = (float*)d_out;                  // [16,2048,256]
    float* h   = (float*)d_ws;                   // 64 MB scratch

    hipLaunchKernelGGL(h_gemm_kernel, dim3((Bc * Nn) / 8), dim3(NTH), 0, stream,
                       nodes, W, h);
    hipLaunchKernelGGL(gat_attn_kernel, dim3(Bc * (Nn / QT)), dim3(NTH), 0, stream,
                       h, nodes, adj, bias, out);
}

// Round 3
// 629.485 us; speedup vs baseline: 4.2487x; 4.2487x over previous
//
#include <hip/hip_runtime.h>
#include <math.h>

typedef _Float16 half8 __attribute__((ext_vector_type(8)));
typedef float    f32x4 __attribute__((ext_vector_type(4)));

constexpr int Bc = 16, Nn = 2048, Dd = 256;
constexpr int QTI = 64;   // q rows per block (4 waves x 16)
constexpr int MC  = 64;   // m-chunk per iteration

__device__ _Float16 g_Wt[Dd * Dd];   // W^T, f16  (o-major: g_Wt[o][i])

// ---------- transpose W (fp32 [i][o]) -> g_Wt (f16 [o][i]) ----------
__global__ void __launch_bounds__(256)
wt_transpose_kernel(const float* __restrict__ W) {
    __shared__ float ts[64][65];
    const int t = threadIdx.x;
    const int r0 = blockIdx.x * 64;   // i tile
    const int c0 = blockIdx.y * 64;   // o tile
    for (int idx = t; idx < 64 * 64; idx += 256) {
        const int i = idx >> 6, j = idx & 63;
        ts[i][j] = W[(r0 + i) * Dd + c0 + j];
    }
    __syncthreads();
    for (int idx = t; idx < 64 * 64; idx += 256) {
        const int c = idx >> 6, rl = idx & 63;
        g_Wt[(c0 + c) * Dd + r0 + rl] = (_Float16)ts[rl][c];
    }
}

// ---------- transpose nodes (fp32 [b][n][d]) -> vt (f16 [b][d][n]) ----------
__global__ void __launch_bounds__(256)
nodes_transpose_kernel(const float* __restrict__ nodes, _Float16* __restrict__ vt) {
    __shared__ float ts[64][65];
    const int t  = threadIdx.x;
    const int n0 = blockIdx.x * 64;
    const int d0 = blockIdx.y * 64;
    const int b  = blockIdx.z;
    const float* src = nodes + (size_t)b * Nn * Dd;
    _Float16*    dst = vt    + (size_t)b * Dd * Nn;
    for (int idx = t; idx < 64 * 64; idx += 256) {
        const int i = idx >> 6, j = idx & 63;
        ts[i][j] = src[(size_t)(n0 + i) * Dd + d0 + j];
    }
    __syncthreads();
    for (int idx = t; idx < 64 * 64; idx += 256) {
        const int d = idx >> 6, nl = idx & 63;
        dst[(size_t)(d0 + d) * Nn + n0 + nl] = (_Float16)ts[nl][d];
    }
}

// ---------- h = nodes @ W (MFMA f16, fp32 accum), h stored f16 ----------
// 512 blocks x 256 thr; wave owns 16 rows; 16 o-tiles x 8 k-steps = 128 MFMAs.
__global__ void __launch_bounds__(256)
hgemm_kernel(const float* __restrict__ nodes, _Float16* __restrict__ h16) {
    const int t = threadIdx.x, w = t >> 6, lane = t & 63;
    const int quad = lane >> 4, l16 = lane & 15;
    const size_t row0 = (size_t)blockIdx.x * 64 + 16 * w;

    half8 aq[8];
    {
        const float* src = nodes + (row0 + l16) * Dd + quad * 8;
        #pragma unroll
        for (int kf = 0; kf < 8; ++kf) {
            const f32x4 a0 = *(const f32x4*)(src + kf * 32);
            const f32x4 a1 = *(const f32x4*)(src + kf * 32 + 4);
            half8 a;
            a[0] = (_Float16)a0[0]; a[1] = (_Float16)a0[1];
            a[2] = (_Float16)a0[2]; a[3] = (_Float16)a0[3];
            a[4] = (_Float16)a1[0]; a[5] = (_Float16)a1[1];
            a[6] = (_Float16)a1[2]; a[7] = (_Float16)a1[3];
            aq[kf] = a;
        }
    }
    f32x4 acc[16];
    #pragma unroll
    for (int ot = 0; ot < 16; ++ot) acc[ot] = (f32x4){0.f, 0.f, 0.f, 0.f};

    #pragma unroll
    for (int kf = 0; kf < 8; ++kf) {
        #pragma unroll
        for (int ot = 0; ot < 16; ++ot) {
            const half8 bw = *(const half8*)&g_Wt[(ot * 16 + l16) * Dd + kf * 32 + quad * 8];
            acc[ot] = __builtin_amdgcn_mfma_f32_16x16x32_f16(aq[kf], bw, acc[ot], 0, 0, 0);
        }
    }
    #pragma unroll
    for (int ot = 0; ot < 16; ++ot)
        #pragma unroll
        for (int r = 0; r < 4; ++r)
            h16[(row0 + quad * 4 + r) * Dd + ot * 16 + l16] = (_Float16)acc[ot][r];
}

// ---------- fused flash-style GAT attention ----------
// Block = 64 q-rows of one batch; 4 waves. Per m-chunk (64):
//   stage hm(f16)+adj(f32) in LDS -> QK^T MFMA (wave owns 16 q-rows)
//   -> leaky*adj -> online softmax in C-layout regs -> P via LDS ->
//   PV MFMA d-split across waves (B-frags direct from global Vt).
__global__ void __launch_bounds__(256)
gat_attn_kernel(const _Float16* __restrict__ h, const _Float16* __restrict__ vt,
                const float* __restrict__ adj, const float* __restrict__ bias,
                float* __restrict__ out) {
    __shared__ _Float16 hm_s[MC][264];    // 256+8 pad -> 2-way (free) b128 reads
    __shared__ float    adj_s[QTI][68];   // 64+4 pad -> 2-way (free) b32 reads
    __shared__ _Float16 p_s[QTI][72];     // 64+8 pad
    __shared__ float    alpha_s[QTI];
    __shared__ float    l_s[QTI];

    const int t = threadIdx.x, w = t >> 6, lane = t & 63;
    const int quad = lane >> 4, l16 = lane & 15;
    const int b  = blockIdx.x & 15;        // batch -> XCD affinity
    const int q0 = (blockIdx.x >> 4) * QTI;

    const _Float16* hb = h   + (size_t)b * Nn * Dd;
    const _Float16* vb = vt  + (size_t)b * Dd * Nn;
    const float*    ab = adj + (size_t)b * Nn * Nn;

    // persistent A-frags: wave w owns q rows q0+16w .. +15
    half8 aq[8];
    {
        const _Float16* s = hb + (size_t)(q0 + 16 * w + l16) * Dd + quad * 8;
        #pragma unroll
        for (int kf = 0; kf < 8; ++kf) aq[kf] = *(const half8*)(s + kf * 32);
    }

    f32x4 ot[4][4];   // [q-tile][d-tile], O rows = all 64 q, cols = wave's 64 d
    #pragma unroll
    for (int qt = 0; qt < 4; ++qt)
        #pragma unroll
        for (int dt = 0; dt < 4; ++dt) ot[qt][dt] = (f32x4){0.f, 0.f, 0.f, 0.f};
    float M[4] = {-1e30f, -1e30f, -1e30f, -1e30f};
    float L[4] = {0.f, 0.f, 0.f, 0.f};

    for (int mb = 0; mb < Nn; mb += MC) {
        // ---- stage hm chunk (64x256 f16 = 32KB) and adj tile (64x64 f32) ----
        #pragma unroll
        for (int ii = 0; ii < 8; ++ii) {
            const int i = t + ii * 256;
            const int m = i >> 5, c = i & 31;
            *(half8*)&hm_s[m][c * 8] = *(const half8*)(hb + (size_t)(mb + m) * Dd + c * 8);
        }
        #pragma unroll
        for (int ii = 0; ii < 4; ++ii) {
            const int i = t + ii * 256;
            const int q = i >> 4, c = i & 15;
            *(f32x4*)&adj_s[q][c * 4] = *(const f32x4*)(ab + (size_t)(q0 + q) * Nn + mb + c * 4);
        }
        __syncthreads();

        // ---- QK^T: S strip 16(q) x 64(m) per wave; wave's rows = 16w..16w+15 ----
        f32x4 st[4];
        #pragma unroll
        for (int mt = 0; mt < 4; ++mt) st[mt] = (f32x4){0.f, 0.f, 0.f, 0.f};
        #pragma unroll
        for (int kf = 0; kf < 8; ++kf)
            #pragma unroll
            for (int mt = 0; mt < 4; ++mt) {
                const half8 bm = *(const half8*)&hm_s[mt * 16 + l16][kf * 32 + quad * 8];
                st[mt] = __builtin_amdgcn_mfma_f32_16x16x32_f16(aq[kf], bm, st[mt], 0, 0, 0);
            }

        // ---- leaky_relu * adj + online softmax (C layout: row=quad*4+r, col=l16)
        //      absolute tile row for this wave = 16*w + quad*4 + r  ----
        float rm[4] = {-1e30f, -1e30f, -1e30f, -1e30f};
        #pragma unroll
        for (int mt = 0; mt < 4; ++mt)
            #pragma unroll
            for (int r = 0; r < 4; ++r) {
                float s = st[mt][r];
                s = (s >= 0.f) ? s : 0.2f * s;
                s *= adj_s[16 * w + quad * 4 + r][mt * 16 + l16];   // FIX: +16*w
                st[mt][r] = s;
                rm[r] = fmaxf(rm[r], s);
            }
        #pragma unroll
        for (int off = 1; off < 16; off <<= 1)
            #pragma unroll
            for (int r = 0; r < 4; ++r) rm[r] = fmaxf(rm[r], __shfl_xor(rm[r], off));
        float alpha[4], rs[4] = {0.f, 0.f, 0.f, 0.f};
        #pragma unroll
        for (int r = 0; r < 4; ++r) {
            const float nm = fmaxf(M[r], rm[r]);
            alpha[r] = __expf(M[r] - nm);
            M[r] = nm;
        }
        #pragma unroll
        for (int mt = 0; mt < 4; ++mt)
            #pragma unroll
            for (int r = 0; r < 4; ++r) {
                const float p = __expf(st[mt][r] - M[r]);
                st[mt][r] = p;
                rs[r] += p;
            }
        #pragma unroll
        for (int off = 1; off < 16; off <<= 1)
            #pragma unroll
            for (int r = 0; r < 4; ++r) rs[r] += __shfl_xor(rs[r], off);
        #pragma unroll
        for (int r = 0; r < 4; ++r) L[r] = L[r] * alpha[r] + rs[r];

        // P -> LDS (f16), alpha -> LDS
        #pragma unroll
        for (int mt = 0; mt < 4; ++mt)
            #pragma unroll
            for (int r = 0; r < 4; ++r)
                p_s[16 * w + quad * 4 + r][mt * 16 + l16] = (_Float16)st[mt][r];
        if (l16 == 0)
            #pragma unroll
            for (int r = 0; r < 4; ++r) alpha_s[16 * w + quad * 4 + r] = alpha[r];
        __syncthreads();

        // ---- PV: wave's d-slice = w*64..+63; rescale O then accumulate ----
        #pragma unroll
        for (int qt = 0; qt < 4; ++qt)
            #pragma unroll
            for (int r = 0; r < 4; ++r) {
                const float a = alpha_s[qt * 16 + quad * 4 + r];
                #pragma unroll
                for (int dt = 0; dt < 4; ++dt) ot[qt][dt][r] *= a;
            }
        #pragma unroll
        for (int ks = 0; ks < 2; ++ks) {
            half8 pa[4];
            #pragma unroll
            for (int qt = 0; qt < 4; ++qt)
                pa[qt] = *(const half8*)&p_s[qt * 16 + l16][ks * 32 + quad * 8];
            #pragma unroll
            for (int dt = 0; dt < 4; ++dt) {
                const half8 vfr = *(const half8*)(vb +
                    (size_t)(w * 64 + dt * 16 + l16) * Nn + mb + ks * 32 + quad * 8);
                #pragma unroll
                for (int qt = 0; qt < 4; ++qt)
                    ot[qt][dt] = __builtin_amdgcn_mfma_f32_16x16x32_f16(pa[qt], vfr, ot[qt][dt], 0, 0, 0);
            }
        }
        // next iter's stage writes hm_s/adj_s only; p_s/alpha_s protected by the
        // post-stage barrier. Two barriers per iteration suffice.
    }

    if (l16 == 0)
        #pragma unroll
        for (int r = 0; r < 4; ++r) l_s[16 * w + quad * 4 + r] = L[r];
    __syncthreads();

    #pragma unroll
    for (int qt = 0; qt < 4; ++qt)
        #pragma unroll
        for (int r = 0; r < 4; ++r) {
            const float invl = 1.f / l_s[qt * 16 + quad * 4 + r];
            const size_t q = (size_t)q0 + qt * 16 + quad * 4 + r;
            #pragma unroll
            for (int dt = 0; dt < 4; ++dt) {
                const int d = w * 64 + dt * 16 + l16;
                out[((size_t)b * Nn + q) * Dd + d] = ot[qt][dt][r] * invl + bias[d];
            }
        }
}

extern "C" void kernel_launch(void* const* d_in, const int* in_sizes, int n_in,
                              void* d_out, int out_size, void* d_ws, size_t ws_size,
                              hipStream_t stream) {
    const float* nodes = (const float*)d_in[0];  // [16,2048,256]
    const float* adj   = (const float*)d_in[1];  // [16,2048,2048]
    const float* W     = (const float*)d_in[2];  // [256,256]
    const float* bias  = (const float*)d_in[3];  // [256]
    float* out = (float*)d_out;

    _Float16* h16 = (_Float16*)d_ws;                       // 16.78 MB
    _Float16* vtp = h16 + (size_t)Bc * Nn * Dd;            // 16.78 MB (total 33.55 MB)

    hipLaunchKernelGGL(wt_transpose_kernel, dim3(4, 4), dim3(256), 0, stream, W);
    hipLaunchKernelGGL(nodes_transpose_kernel, dim3(32, 4, 16), dim3(256), 0, stream, nodes, vtp);
    hipLaunchKernelGGL(hgemm_kernel, dim3(512), dim3(256), 0, stream, nodes, h16);
    hipLaunchKernelGGL(gat_attn_kernel, dim3(512), dim3(256), 0, stream, h16, vtp, adj, bias, out);
}